// Round 2
// baseline (181.133 us; speedup 1.0000x reference)
//
#include <hip/hip_runtime.h>

#define S_LEN 4096
#define BATCH 2
#define EMB   768
#define NH    12
#define HDIM  64
#define WIN   256

using f32x4  = __attribute__((ext_vector_type(4))) float;
using bf16x8 = __attribute__((ext_vector_type(8))) short;
using u16x8  = __attribute__((ext_vector_type(8))) unsigned short;

__device__ __forceinline__ unsigned short f2bf(float x) {
    unsigned int u = __float_as_uint(x);
    return (unsigned short)((u + 0x7fffu + ((u >> 16) & 1u)) >> 16);
}

// ---------------- fp32 -> bf16 convert, 8 elems/thread ----------------
__global__ void cvt_kernel(const float* __restrict__ in,
                           unsigned short* __restrict__ out, int n8) {
    int i = blockIdx.x * blockDim.x + threadIdx.x;
    if (i >= n8) return;
    const float4* p = reinterpret_cast<const float4*>(in) + (size_t)i * 2;
    float4 a = p[0];
    float4 b = p[1];
    u16x8 o;
    o[0] = f2bf(a.x); o[1] = f2bf(a.y); o[2] = f2bf(a.z); o[3] = f2bf(a.w);
    o[4] = f2bf(b.x); o[5] = f2bf(b.y); o[6] = f2bf(b.z); o[7] = f2bf(b.w);
    reinterpret_cast<u16x8*>(out)[i] = o;
}

// three weights in one launch (blockIdx.y selects)
__global__ void cvt3_kernel(const float* __restrict__ w0, const float* __restrict__ w1,
                            const float* __restrict__ w2,
                            unsigned short* __restrict__ o0, unsigned short* __restrict__ o1,
                            unsigned short* __restrict__ o2, int n8) {
    int i = blockIdx.x * blockDim.x + threadIdx.x;
    if (i >= n8) return;
    const float* in = (blockIdx.y == 0) ? w0 : (blockIdx.y == 1) ? w1 : w2;
    unsigned short* out = (blockIdx.y == 0) ? o0 : (blockIdx.y == 1) ? o1 : o2;
    const float4* p = reinterpret_cast<const float4*>(in) + (size_t)i * 2;
    float4 a = p[0];
    float4 b = p[1];
    u16x8 o;
    o[0] = f2bf(a.x); o[1] = f2bf(a.y); o[2] = f2bf(a.z); o[3] = f2bf(a.w);
    o[4] = f2bf(b.x); o[5] = f2bf(b.y); o[6] = f2bf(b.z); o[7] = f2bf(b.w);
    reinterpret_cast<u16x8*>(out)[i] = o;
}

// ---------------- fused QKV GEMM (2-phase double-buffered) ----------------
// C[m,n] = sum_k A[m,k] * W[n,k]  (B^T form), M=8192, K=768, N=3*768
// tile 128x128x32, 4 waves 2x2, each wave 64x64 (4x4 frags of 16x16)
#define GBM 128
#define GBN 128
#define GBK 32

#define STAGE_QKV(buf, k0) do {                                                              \
    _Pragma("unroll")                                                                        \
    for (int rep = 0; rep < 2; ++rep) {                                                      \
        int r0 = wave * 32 + rep * 16;                                                       \
        const char* ga = Abase + (size_t)(r0 + srow) * (EMB * 2) + (k0) * 2 + sbyte;         \
        const char* gb = Bbase + (size_t)(r0 + srow) * (EMB * 2) + (k0) * 2 + sbyte;         \
        __builtin_amdgcn_global_load_lds(                                                    \
            (const __attribute__((address_space(1))) unsigned int*)ga,                       \
            (__attribute__((address_space(3))) unsigned int*)&Asm[buf][r0 * GBK], 16, 0, 0); \
        __builtin_amdgcn_global_load_lds(                                                    \
            (const __attribute__((address_space(1))) unsigned int*)gb,                       \
            (__attribute__((address_space(3))) unsigned int*)&Bsm[buf][r0 * GBK], 16, 0, 0); \
    }                                                                                        \
} while (0)

__global__ __launch_bounds__(256) void qkv_gemm(
    const unsigned short* __restrict__ A,
    const unsigned short* __restrict__ Wq,
    const unsigned short* __restrict__ Wk,
    const unsigned short* __restrict__ Wv,
    const float* __restrict__ bq,
    const float* __restrict__ bk,
    const float* __restrict__ bv,
    unsigned short* __restrict__ qo,   // [B][H][S][HD]
    unsigned short* __restrict__ ko,   // [B][H][S][HD]
    unsigned short* __restrict__ vo)   // [B][H][HD][S]  (transposed)
{
    __shared__ unsigned short Asm[2][GBM * GBK];
    __shared__ unsigned short Bsm[2][GBN * GBK];
    const int tid  = threadIdx.x;
    const int wave = tid >> 6, lane = tid & 63;
    const int mblk = blockIdx.x;           // 0..63
    const int nblk = blockIdx.y;           // 0..17
    const int wsel = nblk / 6;             // 0=Q 1=K 2=V
    const int nloc0 = (nblk % 6) * GBN;    // 0..640 within the weight
    const unsigned short* Wp = (wsel == 0) ? Wq : ((wsel == 1) ? Wk : Wv);
    const int wm = wave >> 1, wn = wave & 1;

    f32x4 acc[4][4];
#pragma unroll
    for (int i = 0; i < 4; ++i)
#pragma unroll
        for (int j = 0; j < 4; ++j)
            acc[i][j] = (f32x4){0.f, 0.f, 0.f, 0.f};

    const int frow = lane & 15;
    const int fcol = (lane >> 4) * 8;
    const int srow  = lane >> 2;          // 0..15 within a 16-row wave-load
    const int sbyte = (lane & 3) * 16;    // 0..48 byte offset within 64B row

    const char* Abase = (const char*)(A  + (size_t)(mblk * GBM) * EMB);
    const char* Bbase = (const char*)(Wp + (size_t)nloc0 * EMB);

    // prologue: stage K-step 0 into buffer 0
    STAGE_QKV(0, 0);
    asm volatile("s_waitcnt vmcnt(0)" ::: "memory");
    __syncthreads();

    int cur = 0;
    for (int k0 = 0; k0 < EMB; k0 += GBK) {
        const int nk = k0 + GBK;
        if (nk < EMB) STAGE_QKV(cur ^ 1, nk);   // prefetch next tile (overlaps compute)

        bf16x8 af[4], bfr[4];
#pragma unroll
        for (int mi = 0; mi < 4; ++mi)
            af[mi] = *reinterpret_cast<const bf16x8*>(&Asm[cur][(wm * 64 + mi * 16 + frow) * GBK + fcol]);
#pragma unroll
        for (int ni = 0; ni < 4; ++ni)
            bfr[ni] = *reinterpret_cast<const bf16x8*>(&Bsm[cur][(wn * 64 + ni * 16 + frow) * GBK + fcol]);
#pragma unroll
        for (int mi = 0; mi < 4; ++mi)
#pragma unroll
            for (int ni = 0; ni < 4; ++ni)
                acc[mi][ni] = __builtin_amdgcn_mfma_f32_16x16x32_bf16(af[mi], bfr[ni], acc[mi][ni], 0, 0, 0);

        if (nk < EMB) {
            asm volatile("s_waitcnt vmcnt(0)" ::: "memory");
            __syncthreads();
            cur ^= 1;
        }
    }

    // epilogue
    const float* bias = (wsel == 0) ? bq : ((wsel == 1) ? bk : bv);
    const int rowg = (lane >> 4) * 4;
#pragma unroll
    for (int mi = 0; mi < 4; ++mi) {
        int mbase = mblk * GBM + wm * 64 + mi * 16 + rowg;
#pragma unroll
        for (int ni = 0; ni < 4; ++ni) {
            int nl = nloc0 + wn * 64 + ni * 16 + frow;   // 0..767
            float bb = bias[nl];
            int h = nl >> 6, hd = nl & 63;
#pragma unroll
            for (int r = 0; r < 4; ++r) {
                int mm = mbase + r;
                int b = mm >> 12, s = mm & 4095;
                float v = acc[mi][ni][r] + bb;
                if (wsel == 0) {
                    v *= 0.125f;
                    qo[((size_t)(b * NH + h) * S_LEN + s) * HDIM + hd] = f2bf(v);
                } else if (wsel == 1) {
                    ko[((size_t)(b * NH + h) * S_LEN + s) * HDIM + hd] = f2bf(v);
                } else {
                    vo[((size_t)(b * NH + h) * HDIM + hd) * S_LEN + s] = f2bf(v);
                }
            }
        }
    }
}

// ---------------- banded flash attention (no K/V staging, barrier-free) ----------------
// block = (b, h, 64 queries); 4 waves x 16 rows; chunk loop pruned to in-range chunks,
// so every processed key index is in [0, S) -> only the window test masks.
#define QB  64
#define KC  64
#define NCH 9

__global__ __launch_bounds__(256) void banded_attn(
    const unsigned short* __restrict__ qg,   // [B][H][S][HD]
    const unsigned short* __restrict__ kg,   // [B][H][S][HD]
    const unsigned short* __restrict__ vtg,  // [B][H][HD][S]
    float* __restrict__ out)                 // [B][S][E]
{
    __shared__ unsigned short Psm[4][16 * KC];       // per-wave [qrow][key] swizzled

    const int tid  = threadIdx.x;
    const int wave = tid >> 6, lane = tid & 63;
    const int qb = blockIdx.x * QB;
    const int h  = blockIdx.y, b = blockIdx.z;

    const unsigned short* qp = qg  + (size_t)(b * NH + h) * S_LEN * HDIM;
    const unsigned short* kp = kg  + (size_t)(b * NH + h) * S_LEN * HDIM;
    const unsigned short* vp = vtg + (size_t)(b * NH + h) * HDIM * S_LEN;

    const int frow = lane & 15;
    const int g    = lane >> 4;
    const int fcol = g * 8;

    // Q fragments, held for the whole block
    bf16x8 qf[2];
    {
        const unsigned short* qr = qp + (size_t)(qb + wave * 16 + frow) * HDIM;
        qf[0] = *reinterpret_cast<const bf16x8*>(qr + fcol);
        qf[1] = *reinterpret_cast<const bf16x8*>(qr + 32 + fcol);
    }

    float m_run[4], l_part[4];
    f32x4 o_acc[4];
#pragma unroll
    for (int r = 0; r < 4; ++r) { m_run[r] = -1e30f; l_part[r] = 0.f; }
#pragma unroll
    for (int ni = 0; ni < 4; ++ni) o_acc[ni] = (f32x4){0.f, 0.f, 0.f, 0.f};

    // prune to chunks whose 64 keys are entirely in [0, S): with qb a multiple
    // of 64, chunk start ks = qb-WIN+64c is a multiple of 64, so surviving
    // chunks are fully in-range and every row keeps its full clipped window.
    const int c_start = (qb < WIN) ? ((WIN - qb) >> 6) : 0;
    const int c_end   = min(NCH, (S_LEN + WIN - qb) >> 6);
    const int qrow0 = qb + wave * 16 + g * 4;

    for (int c = c_start; c < c_end; ++c) {
        const int ks = qb - WIN + c * KC;

        // ---- scores S = Q K^T (16 q x 64 keys per wave), K direct from global ----
        f32x4 sc[4];
#pragma unroll
        for (int ni = 0; ni < 4; ++ni) sc[ni] = (f32x4){0.f, 0.f, 0.f, 0.f};
#pragma unroll
        for (int ni = 0; ni < 4; ++ni) {
            const unsigned short* kr = kp + (size_t)(ks + ni * 16 + frow) * HDIM;
            bf16x8 kf0 = *reinterpret_cast<const bf16x8*>(kr + fcol);
            bf16x8 kf1 = *reinterpret_cast<const bf16x8*>(kr + 32 + fcol);
            sc[ni] = __builtin_amdgcn_mfma_f32_16x16x32_bf16(qf[0], kf0, sc[ni], 0, 0, 0);
            sc[ni] = __builtin_amdgcn_mfma_f32_16x16x32_bf16(qf[1], kf1, sc[ni], 0, 0, 0);
        }

        // ---- window mask + online softmax ----
        float pm[4][4];
        float rm[4];
#pragma unroll
        for (int r = 0; r < 4; ++r) rm[r] = -3e38f;
#pragma unroll
        for (int ni = 0; ni < 4; ++ni) {
            int d0 = qrow0 - (ks + ni * 16 + frow);   // qi - key at r=0
#pragma unroll
            for (int r = 0; r < 4; ++r) {
                float s = sc[ni][r];
                bool valid = (unsigned)(d0 + r + WIN) <= (unsigned)(2 * WIN);
                s = valid ? s : -3e38f;
                pm[ni][r] = s;
                rm[r] = fmaxf(rm[r], s);
            }
        }
#pragma unroll
        for (int d = 1; d < 16; d <<= 1)
#pragma unroll
            for (int r = 0; r < 4; ++r)
                rm[r] = fmaxf(rm[r], __shfl_xor(rm[r], d, 64));

        float scale[4];
#pragma unroll
        for (int r = 0; r < 4; ++r) {
            float mn = fmaxf(m_run[r], rm[r]);
            scale[r] = __expf(m_run[r] - mn);
            m_run[r] = mn;
        }
#pragma unroll
        for (int ni = 0; ni < 4; ++ni)
#pragma unroll
            for (int r = 0; r < 4; ++r)
                o_acc[ni][r] *= scale[r];

        // P = exp(S - m), write to per-wave LDS (swizzled), track row sums
#pragma unroll
        for (int r = 0; r < 4; ++r) {
            float psum = 0.f;
#pragma unroll
            for (int ni = 0; ni < 4; ++ni) {
                float p = __expf(pm[ni][r] - m_run[r]);
                psum += p;
                int prow  = g * 4 + r;
                int pelem = (ni * 16 + frow) ^ ((prow & 7) << 3);
                Psm[wave][prow * KC + pelem] = f2bf(p);
            }
            l_part[r] = l_part[r] * scale[r] + psum;
        }

        asm volatile("s_waitcnt lgkmcnt(0)" ::: "memory");
        __builtin_amdgcn_sched_barrier(0);

        // ---- PV: O += P V, V^T direct from global ----
        bf16x8 pf[2];
#pragma unroll
        for (int kk = 0; kk < 2; ++kk) {
            int sw = (frow & 7) << 3;
            pf[kk] = *reinterpret_cast<const bf16x8*>(&Psm[wave][frow * KC + ((kk * 32 + fcol) ^ sw)]);
        }
#pragma unroll
        for (int ni = 0; ni < 4; ++ni) {
            const unsigned short* vr = vp + (size_t)(ni * 16 + frow) * S_LEN + ks;
#pragma unroll
            for (int kk = 0; kk < 2; ++kk) {
                bf16x8 vf = *reinterpret_cast<const bf16x8*>(vr + kk * 32 + fcol);
                o_acc[ni] = __builtin_amdgcn_mfma_f32_16x16x32_bf16(pf[kk], vf, o_acc[ni], 0, 0, 0);
            }
        }
    }

    // ---- finalize: reduce l across the 16-lane group, divide, store fp32 ----
#pragma unroll
    for (int d = 1; d < 16; d <<= 1)
#pragma unroll
        for (int r = 0; r < 4; ++r)
            l_part[r] += __shfl_xor(l_part[r], d, 64);

#pragma unroll
    for (int r = 0; r < 4; ++r) {
        float inv = 1.0f / l_part[r];
        int s = qrow0 + r;
        size_t obase = ((size_t)b * S_LEN + s) * EMB + h * HDIM;
#pragma unroll
        for (int ni = 0; ni < 4; ++ni)
            out[obase + ni * 16 + frow] = o_acc[ni][r] * inv;
    }
}

// ---------------- launcher ----------------
extern "C" void kernel_launch(void* const* d_in, const int* in_sizes, int n_in,
                              void* d_out, int out_size, void* d_ws, size_t ws_size,
                              hipStream_t stream) {
    const float* hs = (const float*)d_in[0];
    const float* Wq = (const float*)d_in[1];
    const float* Wk = (const float*)d_in[2];
    const float* Wv = (const float*)d_in[3];
    const float* bq = (const float*)d_in[4];
    const float* bk = (const float*)d_in[5];
    const float* bv = (const float*)d_in[6];
    float* out = (float*)d_out;

    char* w = (char*)d_ws;
    unsigned short* hs_bf = (unsigned short*)w;                       // 12,582,912 B
    unsigned short* wq_bf = (unsigned short*)(w + 12582912);          // 1,179,648 B each
    unsigned short* wk_bf = wq_bf + 589824;
    unsigned short* wv_bf = wk_bf + 589824;
    unsigned short* q_ws  = (unsigned short*)(w + 12582912 + 3 * 1179648);
    unsigned short* k_ws  = q_ws + 6291456;
    unsigned short* v_ws  = k_ws + 6291456;

    cvt_kernel<<<3072, 256, 0, stream>>>(hs, hs_bf, 786432);
    cvt3_kernel<<<dim3(288, 3), 256, 0, stream>>>(Wq, Wk, Wv, wq_bf, wk_bf, wv_bf, 73728);

    qkv_gemm<<<dim3(64, 18), 256, 0, stream>>>(hs_bf, wq_bf, wk_bf, wv_bf,
                                               bq, bk, bv, q_ws, k_ws, v_ws);

    banded_attn<<<dim3(S_LEN / QB, NH, BATCH), 256, 0, stream>>>(q_ws, k_ws, v_ws, out);
}

// Round 3
// 115.320 us; speedup vs baseline: 1.5707x; 1.5707x over previous
//
#include <hip/hip_runtime.h>

#define S_LEN 4096
#define BATCH 2
#define EMB   768
#define NH    12
#define HDIM  64
#define WIN   256

using f32x4  = __attribute__((ext_vector_type(4))) float;
using bf16x8 = __attribute__((ext_vector_type(8))) short;
using u16x8  = __attribute__((ext_vector_type(8))) unsigned short;

#define AS1 __attribute__((address_space(1)))
#define AS3 __attribute__((address_space(3)))

__device__ __forceinline__ unsigned short f2bf(float x) {
    unsigned int u = __float_as_uint(x);
    return (unsigned short)((u + 0x7fffu + ((u >> 16) & 1u)) >> 16);
}

// ---------------- fp32 -> bf16 convert, 8 elems/thread ----------------
__global__ void cvt_kernel(const float* __restrict__ in,
                           unsigned short* __restrict__ out, int n8) {
    int i = blockIdx.x * blockDim.x + threadIdx.x;
    if (i >= n8) return;
    const float4* p = reinterpret_cast<const float4*>(in) + (size_t)i * 2;
    float4 a = p[0];
    float4 b = p[1];
    u16x8 o;
    o[0] = f2bf(a.x); o[1] = f2bf(a.y); o[2] = f2bf(a.z); o[3] = f2bf(a.w);
    o[4] = f2bf(b.x); o[5] = f2bf(b.y); o[6] = f2bf(b.z); o[7] = f2bf(b.w);
    reinterpret_cast<u16x8*>(out)[i] = o;
}

// three weights in one launch (blockIdx.y selects)
__global__ void cvt3_kernel(const float* __restrict__ w0, const float* __restrict__ w1,
                            const float* __restrict__ w2,
                            unsigned short* __restrict__ o0, unsigned short* __restrict__ o1,
                            unsigned short* __restrict__ o2, int n8) {
    int i = blockIdx.x * blockDim.x + threadIdx.x;
    if (i >= n8) return;
    const float* in = (blockIdx.y == 0) ? w0 : (blockIdx.y == 1) ? w1 : w2;
    unsigned short* out = (blockIdx.y == 0) ? o0 : (blockIdx.y == 1) ? o1 : o2;
    const float4* p = reinterpret_cast<const float4*>(in) + (size_t)i * 2;
    float4 a = p[0];
    float4 b = p[1];
    u16x8 o;
    o[0] = f2bf(a.x); o[1] = f2bf(a.y); o[2] = f2bf(a.z); o[3] = f2bf(a.w);
    o[4] = f2bf(b.x); o[5] = f2bf(b.y); o[6] = f2bf(b.z); o[7] = f2bf(b.w);
    reinterpret_cast<u16x8*>(out)[i] = o;
}

// ---------------- fused QKV GEMM (2-phase double-buffered) ----------------
#define GBM 128
#define GBN 128
#define GBK 32

#define STAGE_QKV(buf, k0) do {                                                              \
    _Pragma("unroll")                                                                        \
    for (int rep = 0; rep < 2; ++rep) {                                                      \
        int r0 = wave * 32 + rep * 16;                                                       \
        const char* ga = Abase + (size_t)(r0 + srow) * (EMB * 2) + (k0) * 2 + sbyte;         \
        const char* gb = Bbase + (size_t)(r0 + srow) * (EMB * 2) + (k0) * 2 + sbyte;         \
        __builtin_amdgcn_global_load_lds(                                                    \
            (const AS1 unsigned int*)ga,                                                     \
            (AS3 unsigned int*)&Asm[buf][r0 * GBK], 16, 0, 0);                               \
        __builtin_amdgcn_global_load_lds(                                                    \
            (const AS1 unsigned int*)gb,                                                     \
            (AS3 unsigned int*)&Bsm[buf][r0 * GBK], 16, 0, 0);                               \
    }                                                                                        \
} while (0)

__global__ __launch_bounds__(256) void qkv_gemm(
    const unsigned short* __restrict__ A,
    const unsigned short* __restrict__ Wq,
    const unsigned short* __restrict__ Wk,
    const unsigned short* __restrict__ Wv,
    const float* __restrict__ bq,
    const float* __restrict__ bk,
    const float* __restrict__ bv,
    unsigned short* __restrict__ qo,   // [B][H][S][HD]
    unsigned short* __restrict__ ko,   // [B][H][S][HD]
    unsigned short* __restrict__ vo)   // [B][H][HD][S]  (transposed)
{
    __shared__ unsigned short Asm[2][GBM * GBK];
    __shared__ unsigned short Bsm[2][GBN * GBK];
    const int tid  = threadIdx.x;
    const int wave = tid >> 6, lane = tid & 63;
    const int mblk = blockIdx.x;           // 0..63
    const int nblk = blockIdx.y;           // 0..17
    const int wsel = nblk / 6;             // 0=Q 1=K 2=V
    const int nloc0 = (nblk % 6) * GBN;    // 0..640 within the weight
    const unsigned short* Wp = (wsel == 0) ? Wq : ((wsel == 1) ? Wk : Wv);
    const int wm = wave >> 1, wn = wave & 1;

    f32x4 acc[4][4];
#pragma unroll
    for (int i = 0; i < 4; ++i)
#pragma unroll
        for (int j = 0; j < 4; ++j)
            acc[i][j] = (f32x4){0.f, 0.f, 0.f, 0.f};

    const int frow = lane & 15;
    const int fcol = (lane >> 4) * 8;
    const int srow  = lane >> 2;          // 0..15 within a 16-row wave-load
    const int sbyte = (lane & 3) * 16;    // 0..48 byte offset within 64B row

    const char* Abase = (const char*)(A  + (size_t)(mblk * GBM) * EMB);
    const char* Bbase = (const char*)(Wp + (size_t)nloc0 * EMB);

    STAGE_QKV(0, 0);
    asm volatile("s_waitcnt vmcnt(0)" ::: "memory");
    __syncthreads();

    int cur = 0;
    for (int k0 = 0; k0 < EMB; k0 += GBK) {
        const int nk = k0 + GBK;
        if (nk < EMB) STAGE_QKV(cur ^ 1, nk);

        bf16x8 af[4], bfr[4];
#pragma unroll
        for (int mi = 0; mi < 4; ++mi)
            af[mi] = *reinterpret_cast<const bf16x8*>(&Asm[cur][(wm * 64 + mi * 16 + frow) * GBK + fcol]);
#pragma unroll
        for (int ni = 0; ni < 4; ++ni)
            bfr[ni] = *reinterpret_cast<const bf16x8*>(&Bsm[cur][(wn * 64 + ni * 16 + frow) * GBK + fcol]);
#pragma unroll
        for (int mi = 0; mi < 4; ++mi)
#pragma unroll
            for (int ni = 0; ni < 4; ++ni)
                acc[mi][ni] = __builtin_amdgcn_mfma_f32_16x16x32_bf16(af[mi], bfr[ni], acc[mi][ni], 0, 0, 0);

        if (nk < EMB) {
            asm volatile("s_waitcnt vmcnt(0)" ::: "memory");
            __syncthreads();
            cur ^= 1;
        }
    }

    const float* bias = (wsel == 0) ? bq : ((wsel == 1) ? bk : bv);
    const int rowg = (lane >> 4) * 4;
#pragma unroll
    for (int mi = 0; mi < 4; ++mi) {
        int mbase = mblk * GBM + wm * 64 + mi * 16 + rowg;
#pragma unroll
        for (int ni = 0; ni < 4; ++ni) {
            int nl = nloc0 + wn * 64 + ni * 16 + frow;   // 0..767
            float bb = bias[nl];
            int h = nl >> 6, hd = nl & 63;
#pragma unroll
            for (int r = 0; r < 4; ++r) {
                int mm = mbase + r;
                int b = mm >> 12, s = mm & 4095;
                float v = acc[mi][ni][r] + bb;
                if (wsel == 0) {
                    v *= 0.125f;
                    qo[((size_t)(b * NH + h) * S_LEN + s) * HDIM + hd] = f2bf(v);
                } else if (wsel == 1) {
                    ko[((size_t)(b * NH + h) * S_LEN + s) * HDIM + hd] = f2bf(v);
                } else {
                    vo[((size_t)(b * NH + h) * HDIM + hd) * S_LEN + s] = f2bf(v);
                }
            }
        }
    }
}

// ---------------- banded flash attention (staged K/V, 8 waves, double-buffered) ----------------
// block = (b, h, 128 queries); 8 waves x 16 rows; chunks of 64 keys, pruned to
// fully in-range chunks (qb and chunk starts are multiples of 64), so no clamping.
// K/V staged via global_load_lds with PRE-SWIZZLED global source (linear LDS dest);
// reads apply the same XOR -> conflict-free ds_read_b128.
#define QB   128
#define KC   64
#define NCHQ ((QB + 2 * WIN) / KC)   // 10

#define STAGE_ATT(buf, ks) do {                                                              \
    const unsigned short* kr_ = kp + (size_t)((ks) + srow) * HDIM + gblk * 8;                \
    __builtin_amdgcn_global_load_lds(                                                        \
        (const AS1 unsigned int*)kr_,                                                        \
        (AS3 unsigned int*)&Ksm[buf][wave * 512], 16, 0, 0);                                 \
    const unsigned short* vr_ = vp + (size_t)srow * S_LEN + (ks) + gblk * 8;                 \
    __builtin_amdgcn_global_load_lds(                                                        \
        (const AS1 unsigned int*)vr_,                                                        \
        (AS3 unsigned int*)&Vsm[buf][wave * 512], 16, 0, 0);                                 \
} while (0)

__global__ __launch_bounds__(512) void banded_attn(
    const unsigned short* __restrict__ qg,   // [B][H][S][HD]
    const unsigned short* __restrict__ kg,   // [B][H][S][HD]
    const unsigned short* __restrict__ vtg,  // [B][H][HD][S]
    float* __restrict__ out)                 // [B][S][E]
{
    __shared__ unsigned short Ksm[2][KC * HDIM];     // [key][hd], swizzled storage
    __shared__ unsigned short Vsm[2][HDIM * KC];     // [hd][key], swizzled storage
    __shared__ unsigned short Psm[8][16 * KC];       // per-wave [qrow][key], swizzled

    const int tid  = threadIdx.x;
    const int wave = tid >> 6, lane = tid & 63;
    const int qb = blockIdx.x * QB;
    const int h  = blockIdx.y, b = blockIdx.z;

    const unsigned short* qp = qg  + (size_t)(b * NH + h) * S_LEN * HDIM;
    const unsigned short* kp = kg  + (size_t)(b * NH + h) * S_LEN * HDIM;
    const unsigned short* vp = vtg + (size_t)(b * NH + h) * HDIM * S_LEN;

    const int frow = lane & 15;
    const int g    = lane >> 4;
    const int fcol = g * 8;

    // staging map: thread t loads 16B; LDS linear slot t*8 elems = row (t>>3), blk (t&7);
    // global source block index is XOR-swizzled so swizzled reads see linear data
    const int srow = tid >> 3;               // 0..63
    const int gblk = (tid & 7) ^ (srow & 7); // pre-swizzled 16B-block index

    // Q fragments, held for the whole block
    bf16x8 qf[2];
    {
        const unsigned short* qr = qp + (size_t)(qb + wave * 16 + frow) * HDIM;
        qf[0] = *reinterpret_cast<const bf16x8*>(qr + fcol);
        qf[1] = *reinterpret_cast<const bf16x8*>(qr + 32 + fcol);
    }

    float m_run[4], l_part[4];
    f32x4 o_acc[4];
#pragma unroll
    for (int r = 0; r < 4; ++r) { m_run[r] = -1e30f; l_part[r] = 0.f; }
#pragma unroll
    for (int ni = 0; ni < 4; ++ni) o_acc[ni] = (f32x4){0.f, 0.f, 0.f, 0.f};

    const int c_start = (qb < WIN) ? ((WIN - qb) >> 6) : 0;
    const int c_end   = min(NCHQ, (S_LEN + WIN - qb) >> 6);
    const int qrow0 = qb + wave * 16 + g * 4;

    // prologue: stage first chunk
    STAGE_ATT(0, qb - WIN + c_start * KC);
    asm volatile("s_waitcnt vmcnt(0)" ::: "memory");
    __syncthreads();

    int cur = 0;
    for (int c = c_start; c < c_end; ++c) {
        const int ks = qb - WIN + c * KC;
        if (c + 1 < c_end) STAGE_ATT(cur ^ 1, ks + KC);   // prefetch next chunk

        // ---- scores S = Q K^T (16 q x 64 keys per wave) ----
        f32x4 sc[4];
#pragma unroll
        for (int ni = 0; ni < 4; ++ni) sc[ni] = (f32x4){0.f, 0.f, 0.f, 0.f};
#pragma unroll
        for (int ni = 0; ni < 4; ++ni) {
            int krow = ni * 16 + frow;
            int sw   = (krow & 7) << 3;
            bf16x8 kf0 = *reinterpret_cast<const bf16x8*>(&Ksm[cur][krow * KC + (fcol ^ sw)]);
            bf16x8 kf1 = *reinterpret_cast<const bf16x8*>(&Ksm[cur][krow * KC + ((32 + fcol) ^ sw)]);
            sc[ni] = __builtin_amdgcn_mfma_f32_16x16x32_bf16(qf[0], kf0, sc[ni], 0, 0, 0);
            sc[ni] = __builtin_amdgcn_mfma_f32_16x16x32_bf16(qf[1], kf1, sc[ni], 0, 0, 0);
        }

        // ---- window mask + online softmax ----
        float pm[4][4];
        float rm[4];
#pragma unroll
        for (int r = 0; r < 4; ++r) rm[r] = -3e38f;
#pragma unroll
        for (int ni = 0; ni < 4; ++ni) {
            int d0 = qrow0 - (ks + ni * 16 + frow);   // qi - key at r=0
#pragma unroll
            for (int r = 0; r < 4; ++r) {
                float s = sc[ni][r];
                bool valid = (unsigned)(d0 + r + WIN) <= (unsigned)(2 * WIN);
                s = valid ? s : -3e38f;
                pm[ni][r] = s;
                rm[r] = fmaxf(rm[r], s);
            }
        }
#pragma unroll
        for (int d = 1; d < 16; d <<= 1)
#pragma unroll
            for (int r = 0; r < 4; ++r)
                rm[r] = fmaxf(rm[r], __shfl_xor(rm[r], d, 64));

        float scale[4];
#pragma unroll
        for (int r = 0; r < 4; ++r) {
            float mn = fmaxf(m_run[r], rm[r]);
            scale[r] = __expf(m_run[r] - mn);
            m_run[r] = mn;
        }
#pragma unroll
        for (int ni = 0; ni < 4; ++ni)
#pragma unroll
            for (int r = 0; r < 4; ++r)
                o_acc[ni][r] *= scale[r];

        // P = exp(S - m) -> per-wave LDS (swizzled), track row sums
#pragma unroll
        for (int r = 0; r < 4; ++r) {
            float psum = 0.f;
#pragma unroll
            for (int ni = 0; ni < 4; ++ni) {
                float p = __expf(pm[ni][r] - m_run[r]);
                psum += p;
                int prow  = g * 4 + r;
                int pelem = (ni * 16 + frow) ^ ((prow & 7) << 3);
                Psm[wave][prow * KC + pelem] = f2bf(p);
            }
            l_part[r] = l_part[r] * scale[r] + psum;
        }

        asm volatile("s_waitcnt lgkmcnt(0)" ::: "memory");
        __builtin_amdgcn_sched_barrier(0);

        // ---- PV: O += P V ----
        bf16x8 pf[2];
#pragma unroll
        for (int kk = 0; kk < 2; ++kk) {
            int sw = (frow & 7) << 3;
            pf[kk] = *reinterpret_cast<const bf16x8*>(&Psm[wave][frow * KC + ((kk * 32 + fcol) ^ sw)]);
        }
#pragma unroll
        for (int ni = 0; ni < 4; ++ni) {
            int vrow = ni * 16 + frow;
            int sw   = (vrow & 7) << 3;
#pragma unroll
            for (int kk = 0; kk < 2; ++kk) {
                bf16x8 vf = *reinterpret_cast<const bf16x8*>(&Vsm[cur][vrow * KC + ((kk * 32 + fcol) ^ sw)]);
                o_acc[ni] = __builtin_amdgcn_mfma_f32_16x16x32_bf16(pf[kk], vf, o_acc[ni], 0, 0, 0);
            }
        }

        asm volatile("s_waitcnt vmcnt(0)" ::: "memory");
        __syncthreads();
        cur ^= 1;
    }

    // ---- finalize: reduce l across the 16-lane group, divide, store fp32 ----
#pragma unroll
    for (int d = 1; d < 16; d <<= 1)
#pragma unroll
        for (int r = 0; r < 4; ++r)
            l_part[r] += __shfl_xor(l_part[r], d, 64);

#pragma unroll
    for (int r = 0; r < 4; ++r) {
        float inv = 1.0f / l_part[r];
        int s = qrow0 + r;
        size_t obase = ((size_t)b * S_LEN + s) * EMB + h * HDIM;
#pragma unroll
        for (int ni = 0; ni < 4; ++ni)
            out[obase + ni * 16 + frow] = o_acc[ni][r] * inv;
    }
}

// ---------------- launcher ----------------
extern "C" void kernel_launch(void* const* d_in, const int* in_sizes, int n_in,
                              void* d_out, int out_size, void* d_ws, size_t ws_size,
                              hipStream_t stream) {
    const float* hs = (const float*)d_in[0];
    const float* Wq = (const float*)d_in[1];
    const float* Wk = (const float*)d_in[2];
    const float* Wv = (const float*)d_in[3];
    const float* bq = (const float*)d_in[4];
    const float* bk = (const float*)d_in[5];
    const float* bv = (const float*)d_in[6];
    float* out = (float*)d_out;

    char* w = (char*)d_ws;
    unsigned short* hs_bf = (unsigned short*)w;                       // 12,582,912 B
    unsigned short* wq_bf = (unsigned short*)(w + 12582912);          // 1,179,648 B each
    unsigned short* wk_bf = wq_bf + 589824;
    unsigned short* wv_bf = wk_bf + 589824;
    unsigned short* q_ws  = (unsigned short*)(w + 12582912 + 3 * 1179648);
    unsigned short* k_ws  = q_ws + 6291456;
    unsigned short* v_ws  = k_ws + 6291456;

    cvt_kernel<<<3072, 256, 0, stream>>>(hs, hs_bf, 786432);
    cvt3_kernel<<<dim3(288, 3), 256, 0, stream>>>(Wq, Wk, Wv, wq_bf, wk_bf, wv_bf, 73728);

    qkv_gemm<<<dim3(64, 18), 256, 0, stream>>>(hs_bf, wq_bf, wk_bf, wv_bf,
                                               bq, bk, bv, q_ws, k_ws, v_ws);

    banded_attn<<<dim3(S_LEN / QB, NH, BATCH), 512, 0, stream>>>(q_ws, k_ws, v_ws, out);
}